// Round 7
// baseline (338.984 us; speedup 1.0000x reference)
//
#include <hip/hip_runtime.h>
#include <math.h>

#define T_LEN 65536

#define DROW 72       // bf16 words per staged data row (64 + 8 pad; rows 16B-aligned)
#define ARS 24        // A-tile row stride in shorts (48B, 16B-aligned -> b128 ok)
#define ASL 392       // shorts per A tile slot (16*24 + 8 pad)
#define BSL 264       // shorts per B tile slot (16 rows x 16 + 8 pad)
#define GSL 260       // dwords per G-column slot (16 cols x 16 + 4 pad)
#define K2 16         // stage-2 chunk length
#define W2 24         // stage-2 warm-up steps
#define PF2 4         // stage-2 prefetch depth

typedef __attribute__((ext_vector_type(8))) short bh8;
typedef __attribute__((ext_vector_type(4))) float f4;

__device__ __forceinline__ unsigned short f2bf(float x) {
    union { float f; unsigned u; } v; v.f = x;
    return (unsigned short)((v.u + 0x7FFFu + ((v.u >> 16) & 1u)) >> 16);  // RNE
}
__device__ __forceinline__ float bf2f(unsigned short s) {
    union { unsigned u; float f; } v; v.u = ((unsigned)s) << 16; return v.f;
}
__device__ __forceinline__ void unp8(bh8 v, float* o) {
    #pragma unroll
    for (int e = 0; e < 8; ++e) o[e] = bf2f((unsigned short)v[e]);
}

// ---- one-time weight swizzle into bf16 MFMA B-fragment order ----
__global__ void wswz_kernel(const float* __restrict__ Wmu, const float* __restrict__ WL,
                            const float* __restrict__ WLx, short* __restrict__ Wsw)
{
    int idx = blockIdx.x * 256 + threadIdx.x;   // 0 .. 66*512-1
    int f = idx >> 9, r = idx & 511;
    int lane = r >> 3, j = r & 7;
    int ks = f & 1, job = f >> 1;
    int k = ks * 32 + ((lane >> 4) << 3) + j;
    int n = job * 16 + (lane & 15);
    float v = (n < 16) ? Wmu[k * 16 + n]
            : (n < 272) ? WL[k * 256 + (n - 16)]
            : WLx[k * 256 + (n - 272)];
    Wsw[idx] = (short)f2bf(v);
}

// ---- fused: MFMA recognition GEMM -> LDS -> per-t factorization ----
// bf16 A/B/P tiles (halved broadcast-read traffic), f32 G columns with a
// single residual-column publish per k (invd folded into P/N/u updates),
// triangular column reads, Dt/Gcol LDS union. 36.8 KB LDS -> 4 blocks/CU.
__global__ __launch_bounds__(256, 2)
void vilds_fused(const float* __restrict__ data, const short* __restrict__ Wsw,
                 const float* __restrict__ bmu, const float* __restrict__ bL,
                 const float* __restrict__ bLx, const float* __restrict__ ns,
                 unsigned short* __restrict__ Nbuf, float* __restrict__ Ubuf,
                 float* __restrict__ PXbuf, float* __restrict__ entOut)
{
    __shared__ __align__(16) char smem[12544 + 8448 + 16640];
    short* At16 = (short*)smem;                    // A tiles bf16 (later P^T)
    short* Bt16 = (short*)(smem + 12544);          // B tiles bf16
    short* Dt   = (short*)(smem + 12544 + 8448);   // staged data (dead after GEMM)
    float* Gcol = (float*)(smem + 12544 + 8448);   // G residual columns (after barrier)

    const int tid = threadIdx.x;
    const int t0 = blockIdx.x * 16;

    // stage data rows t0..t0+16 as bf16
    for (int idx = tid; idx < 17 * 16; idx += 256) {
        int row = idx >> 4, c4 = idx & 15;
        int tr = t0 + row;
        float4 dv = (tr < T_LEN) ? ((const float4*)data)[(size_t)tr * 16 + c4]
                                 : make_float4(0.f, 0.f, 0.f, 0.f);
        short4 b;
        b.x = (short)f2bf(dv.x); b.y = (short)f2bf(dv.y);
        b.z = (short)f2bf(dv.z); b.w = (short)f2bf(dv.w);
        *(short4*)&Dt[row * DROW + c4 * 4] = b;
    }
    __syncthreads();

    // ---- MFMA phase: jobs 0=postX, 1..16=A rows, 17..32=B rows ----
    {
        const int wv = tid >> 6, lane = tid & 63;
        const int col = lane & 15, quad = lane >> 4;
        bh8 a00 = *(const bh8*)&Dt[col * DROW + quad * 8];
        bh8 a01 = *(const bh8*)&Dt[col * DROW + quad * 8 + 32];
        bh8 a10 = *(const bh8*)&Dt[(col + 1) * DROW + quad * 8];
        bh8 a11 = *(const bh8*)&Dt[(col + 1) * DROW + quad * 8 + 32];
        for (int job = wv; job < 33; job += 4) {
            const int isB = (job >= 17);
            bh8 b0 = *(const bh8*)&Wsw[(job * 2 + 0) * 512 + lane * 8];
            bh8 b1 = *(const bh8*)&Wsw[(job * 2 + 1) * 512 + lane * 8];
            float bias;
            if (job == 0)      bias = bmu[col];
            else if (!isB)     bias = bL[(job - 1) * 16 + col] + ((col == job - 1) ? 3.0f : 0.0f);
            else               bias = bLx[(job - 17) * 16 + col];
            f4 acc = { bias, bias, bias, bias };
            acc = __builtin_amdgcn_mfma_f32_16x16x32_bf16(isB ? a10 : a00, b0, acc, 0, 0, 0);
            acc = __builtin_amdgcn_mfma_f32_16x16x32_bf16(isB ? a11 : a01, b1, acc, 0, 0, 0);
            if (job == 0) {
                #pragma unroll
                for (int r = 0; r < 4; ++r)
                    PXbuf[(size_t)(t0 + quad * 4 + r) * 16 + col] = acc[r];
            } else if (!isB) {
                int i = job - 1;
                #pragma unroll
                for (int r = 0; r < 4; ++r)
                    At16[(quad * 4 + r) * ASL + i * ARS + col] = (short)f2bf(acc[r]);
            } else {
                int i = job - 17;
                #pragma unroll
                for (int r = 0; r < 4; ++r)
                    Bt16[(quad * 4 + r) * BSL + i * 16 + col] = (short)f2bf(acc[r]);
            }
        }
    }
    __syncthreads();   // Dt dead from here; Gcol may reuse its storage

    // ---- factorization: group gg (16 lanes, one wave) handles t = t0+gg ----
    const int gg = tid >> 4, li = tid & 15;
    const int t = t0 + gg;
    short* At = &At16[gg * ASL];
    const short* Bt_ = &Bt16[gg * BSL];
    float* Gc = &Gcol[gg * GSL];

    // S = A A^T + 1e-6 I, row li (bf16 A rows, broadcast reads)
    float s[16];
    {
        float a[16];
        bh8 v0 = *(const bh8*)&At[li * ARS];
        bh8 v1 = *(const bh8*)&At[li * ARS + 8];
        unp8(v0, a); unp8(v1, a + 8);
        #pragma unroll
        for (int j = 0; j < 16; ++j) {
            bh8 w0 = *(const bh8*)&At[j * ARS];
            bh8 w1 = *(const bh8*)&At[j * ARS + 8];
            float rr[16];
            unp8(w0, rr); unp8(w1, rr + 8);
            float acc = (j == li) ? 1e-6f : 0.0f;
            #pragma unroll
            for (int k = 0; k < 16; ++k) acc = fmaf(a[k], rr[k], acc);
            s[j] = acc;
        }
    }

    // Cholesky: publish residual column k once; all lanes read it back.
    // invd kept in registers; final G recovered as resid*invd where needed.
    float invd[16];
    float ent = 0.0f;
    #pragma unroll
    for (int k = 0; k < 16; ++k) {
        Gc[k * 16 + li] = s[k];                    // residual column k (row li)
        float cc[16];
        {
            f4 c2 = *(const f4*)&Gc[k * 16 + 8];
            f4 c3 = *(const f4*)&Gc[k * 16 + 12];
            cc[8] = c2[0]; cc[9] = c2[1]; cc[10] = c2[2]; cc[11] = c2[3];
            cc[12] = c3[0]; cc[13] = c3[1]; cc[14] = c3[2]; cc[15] = c3[3];
            if (k < 8) {
                f4 c0 = *(const f4*)&Gc[k * 16 + 0];
                f4 c1 = *(const f4*)&Gc[k * 16 + 4];
                cc[0] = c0[0]; cc[1] = c0[1]; cc[2] = c0[2]; cc[3] = c0[3];
                cc[4] = c1[0]; cc[5] = c1[1]; cc[6] = c1[2]; cc[7] = c1[3];
            }
        }
        float dkk = fmaxf(cc[k], 1e-20f);
        float inv = rsqrtf(dkk);
        invd[k] = inv;
        if (li == k) ent = 0.5f * __logf(dkk);
        float w = s[k] * inv * inv;
        #pragma unroll
        for (int j = k + 1; j < 16; ++j)
            s[j] = fmaf(-w, cc[j], s[j]);          // trailing update
    }

    // P^T = (G^{-1} A)^T: lane li owns column li; residual cols + invd folds
    {
        float p[16];
        #pragma unroll
        for (int i = 0; i < 16; ++i)
            p[i] = bf2f((unsigned short)At[i * ARS + li]);   // A[i][li]
        #pragma unroll
        for (int m = 0; m < 16; ++m) {
            p[m] *= invd[m];                       // final P[m][li]
            if (m < 15) {
                float w = p[m] * invd[m];
                float cc[16];
                f4 c2 = *(const f4*)&Gc[m * 16 + 8];
                f4 c3 = *(const f4*)&Gc[m * 16 + 12];
                cc[8] = c2[0]; cc[9] = c2[1]; cc[10] = c2[2]; cc[11] = c2[3];
                cc[12] = c3[0]; cc[13] = c3[1]; cc[14] = c3[2]; cc[15] = c3[3];
                if (m < 7) {
                    f4 c0 = *(const f4*)&Gc[m * 16 + 0];
                    f4 c1 = *(const f4*)&Gc[m * 16 + 4];
                    cc[0] = c0[0]; cc[1] = c0[1]; cc[2] = c0[2]; cc[3] = c0[3];
                    cc[4] = c1[0]; cc[5] = c1[1]; cc[6] = c1[2]; cc[7] = c1[3];
                }
                #pragma unroll
                for (int j = m + 1; j < 16; ++j)
                    p[j] = fmaf(-cc[j], w, p[j]);
            }
        }
        // overwrite A tile column li with P column li (bf16); wave-synchronous
        #pragma unroll
        for (int k = 0; k < 16; ++k)
            At[k * ARS + li] = (short)f2bf(p[k]);
    }

    // C = BBChol * P, row li (bf16 broadcast rows)
    float cr[16];
    {
        float bt[16];
        bh8 br0 = *(const bh8*)&Bt_[li * 16];
        bh8 br1 = *(const bh8*)&Bt_[li * 16 + 8];
        unp8(br0, bt); unp8(br1, bt + 8);
        #pragma unroll
        for (int j = 0; j < 16; ++j) cr[j] = 0.0f;
        #pragma unroll
        for (int k = 0; k < 16; ++k) {
            bh8 q0 = *(const bh8*)&At[k * ARS];
            bh8 q1 = *(const bh8*)&At[k * ARS + 8];
            float rr[16];
            unp8(q0, rr); unp8(q1, rr + 8);
            float bk = bt[k];
            #pragma unroll
            for (int j = 0; j < 16; ++j)
                cr[j] = fmaf(bk, rr[j], cr[j]);
        }
    }

    // N = -G^{-T} C^T (lane li = column li), u = G^{-T} b (replicated).
    // Residual column i + invd fold: G[m][i] = cc_i[m] * invd[i].
    float n_[16], uu[16];
    {
        float b[16];
        const float4* ns4 = (const float4*)&ns[(size_t)t * 16];
        float4 b0 = ns4[0], b1 = ns4[1], b2 = ns4[2], b3 = ns4[3];
        b[0] = b0.x; b[1] = b0.y; b[2] = b0.z; b[3] = b0.w;
        b[4] = b1.x; b[5] = b1.y; b[6] = b1.z; b[7] = b1.w;
        b[8] = b2.x; b[9] = b2.y; b[10] = b2.z; b[11] = b2.w;
        b[12] = b3.x; b[13] = b3.y; b[14] = b3.z; b[15] = b3.w;
        #pragma unroll
        for (int ii = 0; ii < 16; ++ii) {
            const int i = 15 - ii;
            float tN = 0.0f, tU = 0.0f;
            if (i < 15) {
                float cc[16];
                f4 c2 = *(const f4*)&Gc[i * 16 + 8];
                f4 c3 = *(const f4*)&Gc[i * 16 + 12];
                cc[8] = c2[0]; cc[9] = c2[1]; cc[10] = c2[2]; cc[11] = c2[3];
                cc[12] = c3[0]; cc[13] = c3[1]; cc[14] = c3[2]; cc[15] = c3[3];
                if (i < 7) {
                    f4 c0 = *(const f4*)&Gc[i * 16 + 0];
                    f4 c1 = *(const f4*)&Gc[i * 16 + 4];
                    cc[0] = c0[0]; cc[1] = c0[1]; cc[2] = c0[2]; cc[3] = c0[3];
                    cc[4] = c1[0]; cc[5] = c1[1]; cc[6] = c1[2]; cc[7] = c1[3];
                }
                #pragma unroll
                for (int m = i + 1; m < 16; ++m) {
                    tN = fmaf(cc[m], n_[m], tN);
                    tU = fmaf(cc[m], uu[m], tU);
                }
            }
            n_[i] = -(cr[i] + invd[i] * tN) * invd[i];
            uu[i] = (b[i] - invd[i] * tU) * invd[i];
        }
    }

    if (t < T_LEN - 1) {
        #pragma unroll
        for (int i = 0; i < 16; ++i)
            Nbuf[(size_t)t * 256 + i * 16 + li] = f2bf(n_[i]);   // bf16 N[t][i][j]
    }
    if (li == 0) {
        f4* U4 = (f4*)&Ubuf[(size_t)t * 16];
        f4 u0 = { uu[0], uu[1], uu[2], uu[3] };
        f4 u1 = { uu[4], uu[5], uu[6], uu[7] };
        f4 u2 = { uu[8], uu[9], uu[10], uu[11] };
        f4 u3 = { uu[12], uu[13], uu[14], uu[15] };
        U4[0] = u0; U4[1] = u1; U4[2] = u2; U4[3] = u3;
    }

    // entropy: reduce across the wave, one atomic per wave
    float esum = ent;
    #pragma unroll
    for (int off = 1; off < 64; off <<= 1)
        esum += __shfl_xor(esum, off, 64);
    if ((tid & 63) == 0) atomicAdd(entOut, -esum);
}

// ---- backward recurrence, replicated-x: each lane holds full x[16];
// per step one LDS write + one broadcast b128 regather (1 LDS latency, no
// bpermute chain). 4 chunks per wave. ----
__global__ __launch_bounds__(64, 1)
void vilds_stage2(const unsigned short* __restrict__ Nbuf, const float* __restrict__ Ubuf,
                  const float* __restrict__ PXbuf, float* __restrict__ out)
{
    __shared__ float xs[4 * 20];
    const int lane = threadIdx.x;
    const int i = lane & 15;      // row owned by this lane
    const int c = lane >> 4;      // chunk within wave
    const int cid = blockIdx.x * 4 + c;
    const int a = cid * K2;
    int ts = a + K2 - 1 + W2;
    if (ts > T_LEN - 1) ts = T_LEN - 1;

    float x[16];
    {
        const float4* u4 = (const float4*)&Ubuf[(size_t)ts * 16];
        float4 v0 = u4[0], v1 = u4[1], v2 = u4[2], v3 = u4[3];
        x[0] = v0.x; x[1] = v0.y; x[2] = v0.z; x[3] = v0.w;
        x[4] = v1.x; x[5] = v1.y; x[6] = v1.z; x[7] = v1.w;
        x[8] = v2.x; x[9] = v2.y; x[10] = v2.z; x[11] = v2.w;
        x[12] = v3.x; x[13] = v3.y; x[14] = v3.z; x[15] = v3.w;
    }
    if (ts < a + K2)
        out[1 + (size_t)ts * 16 + i] = x[i] + PXbuf[(size_t)ts * 16 + i];

    bh8 nA[PF2], nB[PF2]; float ub[PF2], pxb[PF2];
    #pragma unroll
    for (int q = 0; q < PF2; ++q) {
        int tt = ts - 1 - q;
        if (tt >= a) {
            nA[q] = *(const bh8*)&Nbuf[(size_t)tt * 256 + i * 16];
            nB[q] = *(const bh8*)&Nbuf[(size_t)tt * 256 + i * 16 + 8];
            ub[q] = Ubuf[(size_t)tt * 16 + i];
            pxb[q] = PXbuf[(size_t)tt * 16 + i];
        }
    }

    for (int tb = ts - 1; tb >= a; tb -= PF2) {
        #pragma unroll
        for (int q = 0; q < PF2; ++q) {
            int t = tb - q;
            if (t >= a) {
                bh8 va = nA[q], vb = nB[q];
                float ut = ub[q], pxt = pxb[q];
                int tp = t - PF2;
                if (tp >= a) {   // prefetch PF2 steps ahead
                    nA[q] = *(const bh8*)&Nbuf[(size_t)tp * 256 + i * 16];
                    nB[q] = *(const bh8*)&Nbuf[(size_t)tp * 256 + i * 16 + 8];
                    ub[q] = Ubuf[(size_t)tp * 16 + i];
                    pxb[q] = PXbuf[(size_t)tp * 16 + i];
                }
                float acc0 = ut, acc1 = 0.0f;
                #pragma unroll
                for (int e = 0; e < 8; e += 2) {
                    acc0 = fmaf(bf2f((unsigned short)va[e]), x[e], acc0);
                    acc1 = fmaf(bf2f((unsigned short)va[e + 1]), x[e + 1], acc1);
                    acc0 = fmaf(bf2f((unsigned short)vb[e]), x[8 + e], acc0);
                    acc1 = fmaf(bf2f((unsigned short)vb[e + 1]), x[9 + e], acc1);
                }
                float xn = acc0 + acc1;            // x_t[i]
                xs[c * 20 + i] = xn;               // wave-synchronous gather
                if (t < a + K2)
                    out[1 + (size_t)t * 16 + i] = xn + pxt;
                const float4* xr = (const float4*)&xs[c * 20];
                float4 w0 = xr[0], w1 = xr[1], w2 = xr[2], w3 = xr[3];
                x[0] = w0.x; x[1] = w0.y; x[2] = w0.z; x[3] = w0.w;
                x[4] = w1.x; x[5] = w1.y; x[6] = w1.z; x[7] = w1.w;
                x[8] = w2.x; x[9] = w2.y; x[10] = w2.z; x[11] = w2.w;
                x[12] = w3.x; x[13] = w3.y; x[14] = w3.z; x[15] = w3.w;
            }
        }
    }
}

extern "C" void kernel_launch(void* const* d_in, const int* in_sizes, int n_in,
                              void* d_out, int out_size, void* d_ws, size_t ws_size,
                              hipStream_t stream)
{
    const float* data = (const float*)d_in[0];
    const float* Wmu  = (const float*)d_in[1];
    const float* bmu  = (const float*)d_in[2];
    const float* WL   = (const float*)d_in[3];
    const float* bL   = (const float*)d_in[4];
    const float* WLx  = (const float*)d_in[5];
    const float* bLx  = (const float*)d_in[6];
    const float* ns   = (const float*)d_in[7];
    float* out = (float*)d_out;

    unsigned short* Nbuf = (unsigned short*)d_ws;                 // T*256 bf16
    float* Ubuf  = (float*)(Nbuf + (size_t)T_LEN * 256);          // T*16 f32
    float* PXbuf = Ubuf + (size_t)T_LEN * 16;                     // T*16 f32
    short* Wsw   = (short*)(PXbuf + (size_t)T_LEN * 16);          // 66*512 bf16

    hipMemsetAsync(d_out, 0, sizeof(float), stream); // zero entropy accumulator
    wswz_kernel<<<dim3(132), dim3(256), 0, stream>>>(Wmu, WL, WLx, Wsw);
    vilds_fused<<<dim3(T_LEN / 16), dim3(256), 0, stream>>>(
        data, Wsw, bmu, bL, bLx, ns, Nbuf, Ubuf, PXbuf, out);
    vilds_stage2<<<dim3(T_LEN / (K2 * 4)), dim3(64), 0, stream>>>(Nbuf, Ubuf, PXbuf, out);
}

// Round 8
// 330.551 us; speedup vs baseline: 1.0255x; 1.0255x over previous
//
#include <hip/hip_runtime.h>
#include <math.h>

#define T_LEN 65536

#define DROW 72       // bf16 words per staged data row (64 + 8 pad)
#define ARS 24        // A-tile row stride in shorts (48B, 16B-aligned)
#define ASL 392       // shorts per A tile slot (16*24 + 8 pad; 784B, 16B-aligned)
#define BSL 264       // shorts per B tile slot (16x16 + 8 pad; 528B, 16B-aligned)
#define GSL 260       // dwords per G-column slot (16x16 + 4 pad)
#define K2 16         // stage-2 chunk length
#define W2 24         // stage-2 warm-up steps
#define PF2 4         // stage-2 prefetch depth

typedef __attribute__((ext_vector_type(8))) short bh8;
typedef __attribute__((ext_vector_type(4))) float f4;
typedef __attribute__((ext_vector_type(16))) float f16v;

__device__ __forceinline__ unsigned short f2bf(float x) {
    union { float f; unsigned u; } v; v.f = x;
    return (unsigned short)((v.u + 0x7FFFu + ((v.u >> 16) & 1u)) >> 16);  // RNE
}
__device__ __forceinline__ float bf2f(unsigned short s) {
    union { unsigned u; float f; } v; v.u = ((unsigned)s) << 16; return v.f;
}

// ---- one-time weight swizzle into bf16 MFMA B-fragment order ----
__global__ void wswz_kernel(const float* __restrict__ Wmu, const float* __restrict__ WL,
                            const float* __restrict__ WLx, short* __restrict__ Wsw)
{
    int idx = blockIdx.x * 256 + threadIdx.x;   // 0 .. 66*512-1
    int f = idx >> 9, r = idx & 511;
    int lane = r >> 3, j = r & 7;
    int ks = f & 1, job = f >> 1;
    int k = ks * 32 + ((lane >> 4) << 3) + j;
    int n = job * 16 + (lane & 15);
    float v = (n < 16) ? Wmu[k * 16 + n]
            : (n < 272) ? WL[k * 256 + (n - 16)]
            : WLx[k * 256 + (n - 272)];
    Wsw[idx] = (short)f2bf(v);
}

// ---- fused: MFMA recognition GEMM -> per-t factorization with MFMA S & C ----
__global__ __launch_bounds__(256, 2)
void vilds_fused(const float* __restrict__ data, const short* __restrict__ Wsw,
                 const float* __restrict__ bmu, const float* __restrict__ bL,
                 const float* __restrict__ bLx, const float* __restrict__ ns,
                 unsigned short* __restrict__ Nbuf, float* __restrict__ Ubuf,
                 float* __restrict__ PXbuf, float* __restrict__ entOut)
{
    __shared__ __align__(16) char smem[12544 + 8448 + 16640];
    short* At16 = (short*)smem;                    // A tiles bf16 (later P^T rows)
    short* Bt16 = (short*)(smem + 12544);          // B tiles bf16 (later C exchange)
    short* Dt   = (short*)(smem + 12544 + 8448);   // staged data (dead after GEMM)
    float* Gcol = (float*)(smem + 12544 + 8448);   // S exchange, then G residual cols

    const int tid = threadIdx.x;
    const int t0 = blockIdx.x * 16;

    // stage data rows t0..t0+16 as bf16
    for (int idx = tid; idx < 17 * 16; idx += 256) {
        int row = idx >> 4, c4 = idx & 15;
        int tr = t0 + row;
        float4 dv = (tr < T_LEN) ? ((const float4*)data)[(size_t)tr * 16 + c4]
                                 : make_float4(0.f, 0.f, 0.f, 0.f);
        short4 b;
        b.x = (short)f2bf(dv.x); b.y = (short)f2bf(dv.y);
        b.z = (short)f2bf(dv.z); b.w = (short)f2bf(dv.w);
        *(short4*)&Dt[row * DROW + c4 * 4] = b;
    }
    __syncthreads();

    // ---- MFMA GEMM phase: jobs 0=postX, 1..16=A rows, 17..32=B rows ----
    {
        const int wv = tid >> 6, lane = tid & 63;
        const int col = lane & 15, quad = lane >> 4;
        bh8 a00 = *(const bh8*)&Dt[col * DROW + quad * 8];
        bh8 a01 = *(const bh8*)&Dt[col * DROW + quad * 8 + 32];
        bh8 a10 = *(const bh8*)&Dt[(col + 1) * DROW + quad * 8];
        bh8 a11 = *(const bh8*)&Dt[(col + 1) * DROW + quad * 8 + 32];
        for (int job = wv; job < 33; job += 4) {
            const int isB = (job >= 17);
            bh8 b0 = *(const bh8*)&Wsw[(job * 2 + 0) * 512 + lane * 8];
            bh8 b1 = *(const bh8*)&Wsw[(job * 2 + 1) * 512 + lane * 8];
            float bias;
            if (job == 0)      bias = bmu[col];
            else if (!isB)     bias = bL[(job - 1) * 16 + col] + ((col == job - 1) ? 3.0f : 0.0f);
            else               bias = bLx[(job - 17) * 16 + col];
            f4 acc = { bias, bias, bias, bias };
            acc = __builtin_amdgcn_mfma_f32_16x16x32_bf16(isB ? a10 : a00, b0, acc, 0, 0, 0);
            acc = __builtin_amdgcn_mfma_f32_16x16x32_bf16(isB ? a11 : a01, b1, acc, 0, 0, 0);
            if (job == 0) {
                #pragma unroll
                for (int r = 0; r < 4; ++r)
                    PXbuf[(size_t)(t0 + quad * 4 + r) * 16 + col] = acc[r];
            } else if (!isB) {
                int i = job - 1;
                #pragma unroll
                for (int r = 0; r < 4; ++r)
                    At16[(quad * 4 + r) * ASL + i * ARS + col] = (short)f2bf(acc[r]);
            } else {
                int i = job - 17;
                #pragma unroll
                for (int r = 0; r < 4; ++r)
                    Bt16[(quad * 4 + r) * BSL + i * 16 + col] = (short)f2bf(acc[r]);
            }
        }
    }
    __syncthreads();   // Dt dead; Gcol free until S exchange

    // ---- factorization ----
    const int lane = tid & 63;
    const int wv   = tid >> 6;
    const int slot = tid >> 4;        // absolute group (t index within block)
    const int li   = tid & 15;
    const int t    = t0 + slot;
    const int c    = lane & 31;       // MFMA column id
    const int h    = lane >> 5;       // row-half selector
    const int gl   = (c >> 4) & 1;    // pair-half parity of column c
    const bool lo  = (lane < 32);

    short* At = &At16[slot * ASL];
    float* Gc = &Gcol[slot * GSL];

    // S = Ã Ãᵀ + eps I via two 32x32x16 self-MFMAs (diag blocks = per-t Gram)
    float s[16];
    {
        f16v z;
        #pragma unroll
        for (int e = 0; e < 16; ++e) z[e] = 0.0f;
        const int sp1 = wv * 4 + (c >> 4);
        const int sp2 = sp1 + 2;
        bh8 f1 = *(const bh8*)&At16[sp1 * ASL + (c & 15) * ARS + h * 8];
        bh8 f2 = *(const bh8*)&At16[sp2 * ASL + (c & 15) * ARS + h * 8];
        f16v d1 = __builtin_amdgcn_mfma_f32_32x32x16_bf16(f1, f1, z, 0, 0, 0);
        f16v d2 = __builtin_amdgcn_mfma_f32_32x32x16_bf16(f2, f2, z, 0, 0, 0);
        // cross-half exchange via Gcol scratch (pre-chol)
        float* CXw = &Gcol[(wv * 4 + (lo ? 2 : 0) + (c >> 4)) * GSL + (c & 15) * 8];
        f4 w0, w1;
        #pragma unroll
        for (int k = 0; k < 4; ++k) {
            w0[k] = lo ? (gl ? d2[k + 8] : d2[k])      : (gl ? d1[k + 8] : d1[k]);
            w1[k] = lo ? (gl ? d2[k + 12] : d2[k + 4]) : (gl ? d1[k + 12] : d1[k + 4]);
        }
        *(f4*)&CXw[0] = w0;
        *(f4*)&CXw[4] = w1;
        f4 r0 = *(const f4*)&Gc[li * 8];
        f4 r1 = *(const f4*)&Gc[li * 8 + 4];
        #pragma unroll
        for (int k = 0; k < 8; ++k) {
            float own = lo ? (gl ? d1[k + 8] : d1[k]) : (gl ? d2[k + 8] : d2[k]);
            float crs = (k < 4) ? r0[k] : r1[k - 4];
            int base = (k & 3) + 8 * (k >> 2);
            s[base]     = h ? crs : own;
            s[base + 4] = h ? own : crs;
        }
        s[li] += 1e-6f;
    }

    // Cholesky: publish residual column k once; invd in registers.
    float invd[16];
    float ent = 0.0f;
    #pragma unroll
    for (int k = 0; k < 16; ++k) {
        Gc[k * 16 + li] = s[k];                    // residual column k (row li)
        float cc[16];
        {
            f4 c2 = *(const f4*)&Gc[k * 16 + 8];
            f4 c3 = *(const f4*)&Gc[k * 16 + 12];
            cc[8] = c2[0]; cc[9] = c2[1]; cc[10] = c2[2]; cc[11] = c2[3];
            cc[12] = c3[0]; cc[13] = c3[1]; cc[14] = c3[2]; cc[15] = c3[3];
            if (k < 8) {
                f4 c0 = *(const f4*)&Gc[k * 16 + 0];
                f4 c1 = *(const f4*)&Gc[k * 16 + 4];
                cc[0] = c0[0]; cc[1] = c0[1]; cc[2] = c0[2]; cc[3] = c0[3];
                cc[4] = c1[0]; cc[5] = c1[1]; cc[6] = c1[2]; cc[7] = c1[3];
            }
        }
        float dkk = fmaxf(cc[k], 1e-20f);
        float inv = rsqrtf(dkk);
        invd[k] = inv;
        if (li == k) ent = 0.5f * __logf(dkk);
        float w = s[k] * inv * inv;
        #pragma unroll
        for (int j = k + 1; j < 16; ++j)
            s[j] = fmaf(-w, cc[j], s[j]);          // trailing update
    }

    // P = G^{-1} Ã, lane li owns column li; then store P^T rows (bf16) over A slot
    {
        float p[16];
        #pragma unroll
        for (int i = 0; i < 16; ++i)
            p[i] = bf2f((unsigned short)At[i * ARS + li]);   // A[i][li]
        #pragma unroll
        for (int m = 0; m < 16; ++m) {
            p[m] *= invd[m];                       // final P[m][li]
            if (m < 15) {
                float w = p[m] * invd[m];
                float cc[16];
                f4 c2 = *(const f4*)&Gc[m * 16 + 8];
                f4 c3 = *(const f4*)&Gc[m * 16 + 12];
                cc[8] = c2[0]; cc[9] = c2[1]; cc[10] = c2[2]; cc[11] = c2[3];
                cc[12] = c3[0]; cc[13] = c3[1]; cc[14] = c3[2]; cc[15] = c3[3];
                if (m < 7) {
                    f4 c0 = *(const f4*)&Gc[m * 16 + 0];
                    f4 c1 = *(const f4*)&Gc[m * 16 + 4];
                    cc[0] = c0[0]; cc[1] = c0[1]; cc[2] = c0[2]; cc[3] = c0[3];
                    cc[4] = c1[0]; cc[5] = c1[1]; cc[6] = c1[2]; cc[7] = c1[3];
                }
                #pragma unroll
                for (int j = m + 1; j < 16; ++j)
                    p[j] = fmaf(-cc[j], w, p[j]);
            }
        }
        bh8 o0, o1;
        #pragma unroll
        for (int k = 0; k < 8; ++k) {
            o0[k] = (short)f2bf(p[k]);
            o1[k] = (short)f2bf(p[k + 8]);
        }
        *(bh8*)&At[li * 16]     = o0;   // P^T row li (column li of P)
        *(bh8*)&At[li * 16 + 8] = o1;
    }

    // C rows via two MFMAs: D = P^T · B̃^T  =>  D col c = row c of C = B̃·P
    float cr[16];
    {
        f16v z;
        #pragma unroll
        for (int e = 0; e < 16; ++e) z[e] = 0.0f;
        const int sp1 = wv * 4 + (c >> 4);
        const int sp2 = sp1 + 2;
        bh8 a1 = *(const bh8*)&At16[sp1 * ASL + (c & 15) * 16 + h * 8];   // P^T rows
        bh8 a2 = *(const bh8*)&At16[sp2 * ASL + (c & 15) * 16 + h * 8];
        bh8 b1 = *(const bh8*)&Bt16[sp1 * BSL + (c & 15) * 16 + h * 8];   // B̃ rows
        bh8 b2 = *(const bh8*)&Bt16[sp2 * BSL + (c & 15) * 16 + h * 8];
        f16v d1 = __builtin_amdgcn_mfma_f32_32x32x16_bf16(a1, b1, z, 0, 0, 0);
        f16v d2 = __builtin_amdgcn_mfma_f32_32x32x16_bf16(a2, b2, z, 0, 0, 0);
        // cross-half exchange via (now dead) B̃ region
        float* CXw = (float*)&Bt16[(wv * 4 + (lo ? 2 : 0) + (c >> 4)) * BSL];
        float* CXr = (float*)&Bt16[slot * BSL];
        f4 w0, w1;
        #pragma unroll
        for (int k = 0; k < 4; ++k) {
            w0[k] = lo ? (gl ? d2[k + 8] : d2[k])      : (gl ? d1[k + 8] : d1[k]);
            w1[k] = lo ? (gl ? d2[k + 12] : d2[k + 4]) : (gl ? d1[k + 12] : d1[k + 4]);
        }
        *(f4*)&CXw[(c & 15) * 8]     = w0;
        *(f4*)&CXw[(c & 15) * 8 + 4] = w1;
        f4 r0 = *(const f4*)&CXr[li * 8];
        f4 r1 = *(const f4*)&CXr[li * 8 + 4];
        #pragma unroll
        for (int k = 0; k < 8; ++k) {
            float own = lo ? (gl ? d1[k + 8] : d1[k]) : (gl ? d2[k + 8] : d2[k]);
            float crs = (k < 4) ? r0[k] : r1[k - 4];
            int base = (k & 3) + 8 * (k >> 2);
            cr[base]     = h ? crs : own;
            cr[base + 4] = h ? own : crs;
        }
    }

    // N = -G^{-T} C^T (lane li = column li), u = G^{-T} b (replicated)
    float n_[16], uu[16];
    #pragma unroll
    for (int ii = 0; ii < 16; ++ii) {
        const int i = 15 - ii;
        float tN = 0.0f, tU = 0.0f;
        if (i < 15) {
            float cc[16];
            f4 c2 = *(const f4*)&Gc[i * 16 + 8];
            f4 c3 = *(const f4*)&Gc[i * 16 + 12];
            cc[8] = c2[0]; cc[9] = c2[1]; cc[10] = c2[2]; cc[11] = c2[3];
            cc[12] = c3[0]; cc[13] = c3[1]; cc[14] = c3[2]; cc[15] = c3[3];
            if (i < 7) {
                f4 c0 = *(const f4*)&Gc[i * 16 + 0];
                f4 c1 = *(const f4*)&Gc[i * 16 + 4];
                cc[0] = c0[0]; cc[1] = c0[1]; cc[2] = c0[2]; cc[3] = c0[3];
                cc[4] = c1[0]; cc[5] = c1[1]; cc[6] = c1[2]; cc[7] = c1[3];
            }
            #pragma unroll
            for (int m = i + 1; m < 16; ++m) {
                tN = fmaf(cc[m], n_[m], tN);
                tU = fmaf(cc[m], uu[m], tU);
            }
        }
        n_[i] = -(cr[i] + invd[i] * tN) * invd[i];
        uu[i] = (ns[(size_t)t * 16 + i] - invd[i] * tU) * invd[i];
    }

    if (t < T_LEN - 1) {
        #pragma unroll
        for (int i = 0; i < 16; ++i)
            Nbuf[(size_t)t * 256 + i * 16 + li] = f2bf(n_[i]);   // bf16 N[t][i][j]
    }
    if (li == 0) {
        f4* U4 = (f4*)&Ubuf[(size_t)t * 16];
        f4 u0 = { uu[0], uu[1], uu[2], uu[3] };
        f4 u1 = { uu[4], uu[5], uu[6], uu[7] };
        f4 u2 = { uu[8], uu[9], uu[10], uu[11] };
        f4 u3 = { uu[12], uu[13], uu[14], uu[15] };
        U4[0] = u0; U4[1] = u1; U4[2] = u2; U4[3] = u3;
    }

    // entropy: reduce across the wave, one atomic per wave
    float esum = ent;
    #pragma unroll
    for (int off = 1; off < 64; off <<= 1)
        esum += __shfl_xor(esum, off, 64);
    if ((tid & 63) == 0) atomicAdd(entOut, -esum);
}

// ---- backward recurrence, replicated-x ----
__global__ __launch_bounds__(64, 1)
void vilds_stage2(const unsigned short* __restrict__ Nbuf, const float* __restrict__ Ubuf,
                  const float* __restrict__ PXbuf, float* __restrict__ out)
{
    __shared__ float xs[4 * 20];
    const int lane = threadIdx.x;
    const int i = lane & 15;      // row owned by this lane
    const int c = lane >> 4;      // chunk within wave
    const int cid = blockIdx.x * 4 + c;
    const int a = cid * K2;
    int ts = a + K2 - 1 + W2;
    if (ts > T_LEN - 1) ts = T_LEN - 1;

    float x[16];
    {
        const float4* u4 = (const float4*)&Ubuf[(size_t)ts * 16];
        float4 v0 = u4[0], v1 = u4[1], v2 = u4[2], v3 = u4[3];
        x[0] = v0.x; x[1] = v0.y; x[2] = v0.z; x[3] = v0.w;
        x[4] = v1.x; x[5] = v1.y; x[6] = v1.z; x[7] = v1.w;
        x[8] = v2.x; x[9] = v2.y; x[10] = v2.z; x[11] = v2.w;
        x[12] = v3.x; x[13] = v3.y; x[14] = v3.z; x[15] = v3.w;
    }
    if (ts < a + K2)
        out[1 + (size_t)ts * 16 + i] = x[i] + PXbuf[(size_t)ts * 16 + i];

    bh8 nA[PF2], nB[PF2]; float ub[PF2], pxb[PF2];
    #pragma unroll
    for (int q = 0; q < PF2; ++q) {
        int tt = ts - 1 - q;
        if (tt >= a) {
            nA[q] = *(const bh8*)&Nbuf[(size_t)tt * 256 + i * 16];
            nB[q] = *(const bh8*)&Nbuf[(size_t)tt * 256 + i * 16 + 8];
            ub[q] = Ubuf[(size_t)tt * 16 + i];
            pxb[q] = PXbuf[(size_t)tt * 16 + i];
        }
    }

    for (int tb = ts - 1; tb >= a; tb -= PF2) {
        #pragma unroll
        for (int q = 0; q < PF2; ++q) {
            int t = tb - q;
            if (t >= a) {
                bh8 va = nA[q], vb = nB[q];
                float ut = ub[q], pxt = pxb[q];
                int tp = t - PF2;
                if (tp >= a) {
                    nA[q] = *(const bh8*)&Nbuf[(size_t)tp * 256 + i * 16];
                    nB[q] = *(const bh8*)&Nbuf[(size_t)tp * 256 + i * 16 + 8];
                    ub[q] = Ubuf[(size_t)tp * 16 + i];
                    pxb[q] = PXbuf[(size_t)tp * 16 + i];
                }
                float acc0 = ut, acc1 = 0.0f;
                #pragma unroll
                for (int e = 0; e < 8; e += 2) {
                    acc0 = fmaf(bf2f((unsigned short)va[e]), x[e], acc0);
                    acc1 = fmaf(bf2f((unsigned short)va[e + 1]), x[e + 1], acc1);
                    acc0 = fmaf(bf2f((unsigned short)vb[e]), x[8 + e], acc0);
                    acc1 = fmaf(bf2f((unsigned short)vb[e + 1]), x[9 + e], acc1);
                }
                float xn = acc0 + acc1;            // x_t[i]
                xs[c * 20 + i] = xn;               // wave-synchronous gather
                if (t < a + K2)
                    out[1 + (size_t)t * 16 + i] = xn + pxt;
                const float4* xr = (const float4*)&xs[c * 20];
                float4 w0 = xr[0], w1 = xr[1], w2 = xr[2], w3 = xr[3];
                x[0] = w0.x; x[1] = w0.y; x[2] = w0.z; x[3] = w0.w;
                x[4] = w1.x; x[5] = w1.y; x[6] = w1.z; x[7] = w1.w;
                x[8] = w2.x; x[9] = w2.y; x[10] = w2.z; x[11] = w2.w;
                x[12] = w3.x; x[13] = w3.y; x[14] = w3.z; x[15] = w3.w;
            }
        }
    }
}

extern "C" void kernel_launch(void* const* d_in, const int* in_sizes, int n_in,
                              void* d_out, int out_size, void* d_ws, size_t ws_size,
                              hipStream_t stream)
{
    const float* data = (const float*)d_in[0];
    const float* Wmu  = (const float*)d_in[1];
    const float* bmu  = (const float*)d_in[2];
    const float* WL   = (const float*)d_in[3];
    const float* bL   = (const float*)d_in[4];
    const float* WLx  = (const float*)d_in[5];
    const float* bLx  = (const float*)d_in[6];
    const float* ns   = (const float*)d_in[7];
    float* out = (float*)d_out;

    unsigned short* Nbuf = (unsigned short*)d_ws;                 // T*256 bf16
    float* Ubuf  = (float*)(Nbuf + (size_t)T_LEN * 256);          // T*16 f32
    float* PXbuf = Ubuf + (size_t)T_LEN * 16;                     // T*16 f32
    short* Wsw   = (short*)(PXbuf + (size_t)T_LEN * 16);          // 66*512 bf16

    hipMemsetAsync(d_out, 0, sizeof(float), stream); // zero entropy accumulator
    wswz_kernel<<<dim3(132), dim3(256), 0, stream>>>(Wmu, WL, WLx, Wsw);
    vilds_fused<<<dim3(T_LEN / 16), dim3(256), 0, stream>>>(
        data, Wsw, bmu, bL, bLx, ns, Nbuf, Ubuf, PXbuf, out);
    vilds_stage2<<<dim3(T_LEN / (K2 * 4)), dim3(64), 0, stream>>>(Nbuf, Ubuf, PXbuf, out);
}